// Round 18
// baseline (37.875 us; speedup 1.0000x reference)
//
#include <hip/hip_runtime.h>

#define TT 262144
#define BB 16
#define SS 65536      // TT/4 quads per batch
#define QPB 1024      // output quads per block = 256 threads x 4 consecutive

// ---------------------------------------------------------------------------
// prep_w: build combined filter W (validated rounds 10-17).
//   out[4u+p] = sum_i W[p][i] * x[4u-64+i],  W[p][i] = 4*C_p[126+p-i]
//   Quad form: out-quad u, tap k=0..32: component p uses W4[33p+k] (dot4)
//   against x-quad (u-16+k).
// ---------------------------------------------------------------------------
__global__ __launch_bounds__(256) void prep_w(const float* __restrict__ H,
                                              const float* __restrict__ G,
                                              float* __restrict__ W) {
    int t = blockIdx.x * 256 + threadIdx.x;   // 0..2303
    int e = t >> 2;
    int k = t & 3;
    bool valid = (e < 4 * 132);
    float acc = 0.f;
    if (valid) {
        int p = e / 132;
        int i = e % 132;
        int dd = 126 + p - i;                 // valid 0..124
        if (dd >= 0 && dd <= 124) {
            int j0 = (3 - p) & 3;
#pragma unroll
            for (int jj = 0; jj < 16; ++jj) {
                int j = j0 + 4 * jj;
                if (j <= 62) {
                    int a = 124 - j - dd;
                    if (a >= 0 && a <= 62) acc += H[k * 63 + a] * G[k * 63 + j];
                }
            }
        }
    }
    acc += __shfl_xor(acc, 1);
    acc += __shfl_xor(acc, 2);
    if (valid && k == 0) W[e] = 4.0f * acc;
}

// one tap k: shared (scalar) W quads applied to 4 accs with window quads
#define TAP(k, x0, x1, x2, x3)                                                 \
    {                                                                          \
        const float4 W0 = W4[(k)];            /* phase 0 -> .x */              \
        const float4 W1 = W4[33 + (k)];       /* phase 1 -> .y */              \
        const float4 W2 = W4[66 + (k)];       /* phase 2 -> .z */              \
        const float4 W3 = W4[99 + (k)];       /* phase 3 -> .w */              \
        a0.x = fmaf(W0.w, (x0).w, fmaf(W0.z, (x0).z, fmaf(W0.y, (x0).y, fmaf(W0.x, (x0).x, a0.x)))); \
        a0.y = fmaf(W1.w, (x0).w, fmaf(W1.z, (x0).z, fmaf(W1.y, (x0).y, fmaf(W1.x, (x0).x, a0.y)))); \
        a0.z = fmaf(W2.w, (x0).w, fmaf(W2.z, (x0).z, fmaf(W2.y, (x0).y, fmaf(W2.x, (x0).x, a0.z)))); \
        a0.w = fmaf(W3.w, (x0).w, fmaf(W3.z, (x0).z, fmaf(W3.y, (x0).y, fmaf(W3.x, (x0).x, a0.w)))); \
        a1.x = fmaf(W0.w, (x1).w, fmaf(W0.z, (x1).z, fmaf(W0.y, (x1).y, fmaf(W0.x, (x1).x, a1.x)))); \
        a1.y = fmaf(W1.w, (x1).w, fmaf(W1.z, (x1).z, fmaf(W1.y, (x1).y, fmaf(W1.x, (x1).x, a1.y)))); \
        a1.z = fmaf(W2.w, (x1).w, fmaf(W2.z, (x1).z, fmaf(W2.y, (x1).y, fmaf(W2.x, (x1).x, a1.z)))); \
        a1.w = fmaf(W3.w, (x1).w, fmaf(W3.z, (x1).z, fmaf(W3.y, (x1).y, fmaf(W3.x, (x1).x, a1.w)))); \
        a2.x = fmaf(W0.w, (x2).w, fmaf(W0.z, (x2).z, fmaf(W0.y, (x2).y, fmaf(W0.x, (x2).x, a2.x)))); \
        a2.y = fmaf(W1.w, (x2).w, fmaf(W1.z, (x2).z, fmaf(W1.y, (x2).y, fmaf(W1.x, (x2).x, a2.y)))); \
        a2.z = fmaf(W2.w, (x2).w, fmaf(W2.z, (x2).z, fmaf(W2.y, (x2).y, fmaf(W2.x, (x2).x, a2.z)))); \
        a2.w = fmaf(W3.w, (x2).w, fmaf(W3.z, (x2).z, fmaf(W3.y, (x2).y, fmaf(W3.x, (x2).x, a2.w)))); \
        a3.x = fmaf(W0.w, (x3).w, fmaf(W0.z, (x3).z, fmaf(W0.y, (x3).y, fmaf(W0.x, (x3).x, a3.x)))); \
        a3.y = fmaf(W1.w, (x3).w, fmaf(W1.z, (x3).z, fmaf(W1.y, (x3).y, fmaf(W1.x, (x3).x, a3.y)))); \
        a3.z = fmaf(W2.w, (x3).w, fmaf(W2.z, (x3).z, fmaf(W2.y, (x3).y, fmaf(W2.x, (x3).x, a3.z)))); \
        a3.w = fmaf(W3.w, (x3).w, fmaf(W3.z, (x3).z, fmaf(W3.y, (x3).y, fmaf(W3.x, (x3).x, a3.w)))); \
    }

template <bool GUARD>
__device__ __forceinline__ float4 ldq(const float4* __restrict__ X4, int q) {
    if (GUARD && (unsigned)q >= (unsigned)SS) return make_float4(0.f, 0.f, 0.f, 0.f);
    return X4[q];
}

// FIR over the thread's 36-quad window, loads DIRECT from global (L1-served).
// r14-validated sliding-window order; GUARD only for blocks 0/63.
template <bool GUARD>
__device__ __forceinline__ void fir_loop(const float4* __restrict__ X4,
                                         const float4* __restrict__ W4,
                                         int g0, float4& a0, float4& a1,
                                         float4& a2, float4& a3) {
    float4 w0 = ldq<GUARD>(X4, g0);
    float4 w1 = ldq<GUARD>(X4, g0 + 1);
    float4 w2 = ldq<GUARD>(X4, g0 + 2);
    float4 w3 = ldq<GUARD>(X4, g0 + 3);
#pragma unroll 1
    for (int mm = 0; mm < 8; ++mm) {
        const int k0 = 4 * mm;
        float4 n0 = ldq<GUARD>(X4, g0 + k0 + 4);
        float4 n1 = ldq<GUARD>(X4, g0 + k0 + 5);
        float4 n2 = ldq<GUARD>(X4, g0 + k0 + 6);
        float4 n3 = ldq<GUARD>(X4, g0 + k0 + 7);
        TAP(k0 + 0, w0, w1, w2, w3)
        TAP(k0 + 1, w1, w2, w3, n0)
        TAP(k0 + 2, w2, w3, n0, n1)
        TAP(k0 + 3, w3, n0, n1, n2)
        w0 = n0; w1 = n1; w2 = n2; w3 = n3;
    }
    TAP(32, w0, w1, w2, w3)              // tail tap: quads 32..35
}

// ---------------------------------------------------------------------------
// Fused PQMF, NO LDS: register sliding window fed straight from global.
// Cross-thread x reuse is L1's job (per-block unique x = 17 KB << 32 KB L1).
// No barrier, no staging phase -> loads interleave with fmacs continuously.
// Phase mapping (validated rounds 2/8-17): component p <- W4[33p + k].
// ---------------------------------------------------------------------------
__global__ __launch_bounds__(256) void pqmf_fused(const float* __restrict__ x,
                                                  const float* __restrict__ Wg,
                                                  const float* __restrict__ Hf,
                                                  const float* __restrict__ Gf,
                                                  float* __restrict__ out) {
    const int tid = threadIdx.x;
    const int bx = blockIdx.x;           // 0..63
    const int b = blockIdx.y;
    const int Q0 = bx * QPB;
    const float4* X4 = reinterpret_cast<const float4*>(x + (size_t)b * TT);
    const float4* W4 = reinterpret_cast<const float4*>(Wg);
    float4* ob4 = reinterpret_cast<float4*>(out + (size_t)b * TT);

    const int g0 = Q0 + 4 * tid - 16;    // window start (global quad index)

    float4 a0 = make_float4(0.f, 0.f, 0.f, 0.f);
    float4 a1 = a0, a2 = a0, a3 = a0;

    if (bx >= 1 && bx <= 62) fir_loop<false>(X4, W4, g0, a0, a1, a2, a3);
    else                     fir_loop<true >(X4, W4, g0, a0, a1, a2, a3);

    const int u0 = Q0 + 4 * tid;
    if ((unsigned)(u0 - 16) < (unsigned)(SS - 32))     ob4[u0]     = a0;
    if ((unsigned)(u0 + 1 - 16) < (unsigned)(SS - 32)) ob4[u0 + 1] = a1;
    if ((unsigned)(u0 + 2 - 16) < (unsigned)(SS - 32)) ob4[u0 + 2] = a2;
    if ((unsigned)(u0 + 3 - 16) < (unsigned)(SS - 32)) ob4[u0 + 3] = a3;

    // ---- edge quads (exact two-stage, global reads; r8/r9-validated) ----
    const bool edgeLo = (bx == 0);
    const bool edgeHi = (bx == 63);
    if (edgeLo || edgeHi) {
        const float* xb = x + (size_t)b * TT;
        const int q_local = tid >> 4;    // 0..15
        const int s_idx = tid & 15;      // 0..15
        const int u = edgeLo ? q_local : (SS - 16 + q_local);
        const int s = u - 7 + s_idx;
        float c0 = 0.f, c1 = 0.f, c2 = 0.f, c3 = 0.f;
        if (s >= 0 && s < SS) {
            const int xbase = 4 * s - 31;
            float s0 = 0.f, s1 = 0.f, s2 = 0.f, s3 = 0.f;
#pragma unroll
            for (int a = 0; a < 63; ++a) {
                int xi = xbase + a;
                float xv = (xi >= 0 && xi < TT) ? xb[xi] : 0.f;
                s0 += xv * Hf[a];
                s1 += xv * Hf[63 + a];
                s2 += xv * Hf[126 + a];
                s3 += xv * Hf[189 + a];
            }
            const int d4 = 4 * (s - u);  // -28..32
            {
                int j = d4 + 31;         // p = 0 (j can be 63 at s=u+8)
                if (j <= 62) c0 = s0 * Gf[j] + s1 * Gf[63 + j] + s2 * Gf[126 + j] + s3 * Gf[189 + j];
            }
            {
                int j = d4 + 30;         // p = 1, j in [2,62]
                c1 = s0 * Gf[j] + s1 * Gf[63 + j] + s2 * Gf[126 + j] + s3 * Gf[189 + j];
            }
            {
                int j = d4 + 29;         // p = 2, j in [1,61]
                c2 = s0 * Gf[j] + s1 * Gf[63 + j] + s2 * Gf[126 + j] + s3 * Gf[189 + j];
            }
            {
                int j = d4 + 28;         // p = 3, j in [0,60]
                c3 = s0 * Gf[j] + s1 * Gf[63 + j] + s2 * Gf[126 + j] + s3 * Gf[189 + j];
            }
        }
#pragma unroll
        for (int m = 8; m >= 1; m >>= 1) {
            c0 += __shfl_xor(c0, m);
            c1 += __shfl_xor(c1, m);
            c2 += __shfl_xor(c2, m);
            c3 += __shfl_xor(c3, m);
        }
        if (s_idx == 0) {
            float4 v = make_float4(4.f * c0, 4.f * c1, 4.f * c2, 4.f * c3);
            ob4[u] = v;
        }
    }
}

extern "C" void kernel_launch(void* const* d_in, const int* in_sizes, int n_in,
                              void* d_out, int out_size, void* d_ws, size_t ws_size,
                              hipStream_t stream) {
    const float* x = (const float*)d_in[0];
    const float* H = (const float*)d_in[1];
    const float* G = (const float*)d_in[2];
    float* outp = (float*)d_out;
    float* W = (float*)d_ws;   // 4*132 floats = 2112 B

    hipLaunchKernelGGL(prep_w, dim3(9), dim3(256), 0, stream, H, G, W);
    hipLaunchKernelGGL(pqmf_fused, dim3(SS / QPB, BB), dim3(256), 0, stream,
                       x, W, H, G, outp);
}